// Round 9
// baseline (109.956 us; speedup 1.0000x reference)
//
#include <hip/hip_runtime.h>
#include <cfloat>

// DMBERT candidate-span max-pool + classifier head. 3-kernel pipeline:
//  K1 chunkmax: cm[b][c][h] = col-max over 16-token chunk (reads hidden once)
//  K2 prefsuf:  pref[b][c] = max over chunks [0,c); suff[b][c] = max over [c,32)
//  K3 pool_gemm: left = max(pref[fcL], rows [fcL*16,cut)),
//                right = max(suff[fcR], rows [cut,fcR*16)) -> only the single
//                cut-chunk (16 rows) + 2 precomputed rows per candidate; then
//                fused GEMM epilogue (16 waves, lanes 0..33 own a label).
// hidden: [B=32, S=512, H=1024] f32; W: [2048,34]; b:[34]
// cand_batch/cand_cut: [N=256] i32 ; out: [N,34] f32

constexpr int S_LEN  = 512;
constexpr int HDIM   = 1024;
constexpr int NLAB   = 34;
constexpr int CHUNK  = 16;
constexpr int NCHUNK = S_LEN / CHUNK;   // 32
constexpr int PSDIM  = NCHUNK + 1;      // 33 entries (pref[0..32], suff[0..32])

__device__ __forceinline__ void fmax4(float4& a, const float4 v) {
    a.x = fmaxf(a.x, v.x); a.y = fmaxf(a.y, v.y);
    a.z = fmaxf(a.z, v.z); a.w = fmaxf(a.w, v.w);
}

// ---- K1: cm[b][c][h] = max over tokens [c*CHUNK, (c+1)*CHUNK)
__global__ __launch_bounds__(256) void chunkmax_kernel(
    const float* __restrict__ hidden, float* __restrict__ cm)
{
    const int blk = blockIdx.x;           // b * NCHUNK + c
    const int b   = blk / NCHUNK;
    const int c   = blk % NCHUNK;
    const int t   = threadIdx.x;          // owns cols 4t..4t+3

    const float* base = hidden + ((size_t)b * S_LEN + (size_t)c * CHUNK) * HDIM + 4 * t;
    float4 m = make_float4(-FLT_MAX, -FLT_MAX, -FLT_MAX, -FLT_MAX);
    #pragma unroll
    for (int s = 0; s < CHUNK; ++s)
        fmax4(m, *reinterpret_cast<const float4*>(base + (size_t)s * HDIM));

    *reinterpret_cast<float4*>(cm + ((size_t)b * NCHUNK + c) * HDIM + 4 * t) = m;
}

// ---- K2: chunk-level prefix/suffix max. grid (32 b, 4 col-quarter), 128 thr.
//      tx<64: forward scan (pref); tx>=64: backward scan (suff). 64 thr x 4
//      cols = 256 cols per quarter.
__global__ __launch_bounds__(128) void prefsuf_kernel(
    const float* __restrict__ cm,
    float* __restrict__ pref,
    float* __restrict__ suff)
{
    const int b    = blockIdx.x;
    const int q    = blockIdx.y;
    const int tx   = threadIdx.x;
    const int dir  = tx >> 6;                 // 0 = forward, 1 = backward
    const int lane = tx & 63;
    const int col  = q * 256 + 4 * lane;

    const float* cmb = cm + (size_t)b * NCHUNK * HDIM + col;
    float4 run = make_float4(-FLT_MAX, -FLT_MAX, -FLT_MAX, -FLT_MAX);

    if (dir == 0) {
        float* pb = pref + (size_t)b * PSDIM * HDIM + col;
        *reinterpret_cast<float4*>(pb) = run;                       // pref[0] = -inf
        #pragma unroll 8
        for (int c = 0; c < NCHUNK; ++c) {
            fmax4(run, *reinterpret_cast<const float4*>(cmb + (size_t)c * HDIM));
            *reinterpret_cast<float4*>(pb + (size_t)(c + 1) * HDIM) = run;
        }
    } else {
        float* sb = suff + (size_t)b * PSDIM * HDIM + col;
        *reinterpret_cast<float4*>(sb + (size_t)NCHUNK * HDIM) = run;  // suff[32] = -inf
        #pragma unroll 8
        for (int c = NCHUNK - 1; c >= 0; --c) {
            fmax4(run, *reinterpret_cast<const float4*>(cmb + (size_t)c * HDIM));
            *reinterpret_cast<float4*>(sb + (size_t)c * HDIM) = run;
        }
    }
}

// ---- K3: pool (pref/suff + single cut-chunk, 4 row-teams) + GEMM (16 waves).
__global__ __launch_bounds__(1024) void pool_gemm3(
    const float* __restrict__ hidden,
    const float* __restrict__ pref,
    const float* __restrict__ suff,
    const float* __restrict__ W,
    const float* __restrict__ bias,
    const int*   __restrict__ cand_batch,
    const int*   __restrict__ cand_cut,
    float*       __restrict__ out)
{
    __shared__ float partL[4][HDIM];     // 16 KB
    __shared__ float partR[4][HDIM];     // 16 KB
    __shared__ float pooled[2 * HDIM];   // 8 KB
    __shared__ float gpart[16][NLAB];    // 2.2 KB

    const int n   = blockIdx.x;
    const int t   = threadIdx.x;         // 0..1023
    const int g   = t >> 8;              // row-team 0..3
    const int tt  = t & 255;             // -> cols 4tt..4tt+3
    const int col = 4 * tt;
    const int b   = cand_batch[n];
    const int cut = cand_cut[n];                 // block-uniform
    const int fcL = cut >> 4;                    // chunks [0,fcL) fully left
    const int rem = cut & 15;
    const int fcR = fcL + (rem ? 1 : 0);         // chunks [fcR,32) fully right

    float4 mL = make_float4(-FLT_MAX, -FLT_MAX, -FLT_MAX, -FLT_MAX);
    float4 mR = mL;

    // precomputed prefix/suffix rows (teams 0 and 1 only)
    if (g == 0)
        mL = *reinterpret_cast<const float4*>(
            pref + ((size_t)b * PSDIM + fcL) * HDIM + col);
    else if (g == 1)
        mR = *reinterpret_cast<const float4*>(
            suff + ((size_t)b * PSDIM + fcR) * HDIM + col);

    // rows of the single chunk containing the cut, team-strided
    if (rem) {
        const int base16 = fcL * CHUNK;
        const float* hbase = hidden + (size_t)b * S_LEN * HDIM + col;
        #pragma unroll
        for (int i = 0; i < 4; ++i) {
            const int s = base16 + g + 4 * i;
            const float4 v = *reinterpret_cast<const float4*>(hbase + (size_t)s * HDIM);
            if (s < cut) fmax4(mL, v); else fmax4(mR, v);
        }
    }

    *reinterpret_cast<float4*>(&partL[g][col]) = mL;
    *reinterpret_cast<float4*>(&partR[g][col]) = mR;
    __syncthreads();

    // 4-way combine: thread t handles pooled cols {t, t+1024}
    pooled[t] = fmaxf(fmaxf(partL[0][t], partL[1][t]),
                      fmaxf(partL[2][t], partL[3][t]));
    pooled[HDIM + t] = fmaxf(fmaxf(partR[0][t], partR[1][t]),
                             fmaxf(partR[2][t], partR[3][t]));
    __syncthreads();

    // GEMM: wave w owns k in [128w, 128w+128); lanes 0..33 own a label.
    const int w    = t >> 6;                     // 0..15
    const int lane = t & 63;
    if (lane < NLAB) {
        const float* p  = pooled + 128 * w;
        const float* Wp = W + (size_t)(128 * w) * NLAB + lane;
        float acc = 0.0f;
        #pragma unroll 8
        for (int k = 0; k < 128; ++k)
            acc = fmaf(p[k], Wp[(size_t)k * NLAB], acc);
        gpart[w][lane] = acc;
    }
    __syncthreads();

    if (t < NLAB) {
        float s = bias[t];
        #pragma unroll
        for (int w2 = 0; w2 < 16; ++w2) s += gpart[w2][t];
        out[(size_t)n * NLAB + t] = s;
    }
}

// ---- Fallback: proven single-kernel path (only if ws too small).
__global__ __launch_bounds__(256) void dmbert_pool_gemm(
    const float* __restrict__ hidden,
    const float* __restrict__ W,
    const float* __restrict__ bias,
    const int*   __restrict__ cand_batch,
    const int*   __restrict__ cand_cut,
    float*       __restrict__ out)
{
    __shared__ float pooled[2 * HDIM];
    __shared__ float partial[4][NLAB];

    const int n   = blockIdx.x;
    const int t   = threadIdx.x;
    const int bi  = cand_batch[n];
    const int cut = cand_cut[n];

    const float* base = hidden + (size_t)bi * S_LEN * HDIM + 4 * t;
    float4 mL = make_float4(-FLT_MAX, -FLT_MAX, -FLT_MAX, -FLT_MAX);
    float4 mR = mL;

    #pragma unroll 4
    for (int s = 0; s < cut; ++s)
        fmax4(mL, *reinterpret_cast<const float4*>(base + (size_t)s * HDIM));
    #pragma unroll 4
    for (int s = cut; s < S_LEN; ++s)
        fmax4(mR, *reinterpret_cast<const float4*>(base + (size_t)s * HDIM));

    *reinterpret_cast<float4*>(&pooled[4 * t])        = mL;
    *reinterpret_cast<float4*>(&pooled[HDIM + 4 * t]) = mR;
    __syncthreads();

    const int w    = t >> 6;
    const int lane = t & 63;
    if (lane < NLAB) {
        const int k0 = w * (2 * HDIM / 4);
        float acc = 0.0f;
        #pragma unroll 8
        for (int k = k0; k < k0 + (2 * HDIM / 4); ++k)
            acc = fmaf(pooled[k], W[(size_t)k * NLAB + lane], acc);
        partial[w][lane] = acc;
    }
    __syncthreads();

    if (t < NLAB) {
        out[(size_t)n * NLAB + t] =
            partial[0][t] + partial[1][t] + partial[2][t] + partial[3][t] + bias[t];
    }
}

extern "C" void kernel_launch(void* const* d_in, const int* in_sizes, int n_in,
                              void* d_out, int out_size, void* d_ws, size_t ws_size,
                              hipStream_t stream) {
    const float* hidden = (const float*)d_in[0];
    const float* W      = (const float*)d_in[1];
    const float* bias   = (const float*)d_in[2];
    const int*   cb     = (const int*)d_in[3];
    const int*   cc     = (const int*)d_in[4];
    float*       outp   = (float*)d_out;

    const int ncand = in_sizes[3];                       // 256
    const int B     = in_sizes[0] / (S_LEN * HDIM);      // 32
    const size_t cm_elems = (size_t)B * NCHUNK * HDIM;   // 1M floats
    const size_t ps_elems = (size_t)B * PSDIM * HDIM;    // 1.056M floats each
    const size_t ws_needed = (cm_elems + 2 * ps_elems) * sizeof(float);  // ~12.3MB

    if (ws_size >= ws_needed) {
        float* cm   = (float*)d_ws;
        float* pref = cm + cm_elems;
        float* suff = pref + ps_elems;
        chunkmax_kernel<<<B * NCHUNK, 256, 0, stream>>>(hidden, cm);
        prefsuf_kernel<<<dim3(B, 4), 128, 0, stream>>>(cm, pref, suff);
        pool_gemm3<<<ncand, 1024, 0, stream>>>(hidden, pref, suff, W, bias, cb, cc, outp);
    } else {
        dmbert_pool_gemm<<<ncand, 256, 0, stream>>>(hidden, W, bias, cb, cc, outp);
    }
}

// Round 10
// 109.951 us; speedup vs baseline: 1.0000x; 1.0000x over previous
//
#include <hip/hip_runtime.h>
#include <cfloat>

// DMBERT candidate-span max-pool + classifier head. 2-kernel pipeline:
//  K1 prefsuf_fused: per (batch, 128-col slice): read all 512 rows once,
//     chunk-max (32 chunks x 16 rows) into LDS, Hillis-Steele fwd/bwd
//     max-scan in LDS, write pref[b][0..32][cols] / suff[b][0..32][cols].
//     No cm round-trip through global. grid 32x8 = 256 blocks x 1024 thr.
//  K2 pool_gemm3: left = max(pref[fcL], rows [fcL*16,cut)),
//     right = max(suff[fcR], rows [cut,fcR*16)); fused GEMM epilogue.
// hidden: [B=32, S=512, H=1024] f32; W: [2048,34]; b:[34]
// cand_batch/cand_cut: [N=256] i32 ; out: [N,34] f32

constexpr int S_LEN  = 512;
constexpr int HDIM   = 1024;
constexpr int NLAB   = 34;
constexpr int CHUNK  = 16;
constexpr int NCHUNK = S_LEN / CHUNK;   // 32
constexpr int PSDIM  = NCHUNK + 1;      // 33 rows (pref[0..32] / suff[0..32])
constexpr int SLICE  = 128;             // cols per K1 block (32 float4)

__device__ __forceinline__ void fmax4(float4& a, const float4 v) {
    a.x = fmaxf(a.x, v.x); a.y = fmaxf(a.y, v.y);
    a.z = fmaxf(a.z, v.z); a.w = fmaxf(a.w, v.w);
}

// ---- K1: fused chunk-max + prefix/suffix scan. b = blockIdx.x, slice = blockIdx.y.
//      Thread t: c = t>>5 (chunk 0..31), j = t&31 (float4-col within slice).
__global__ __launch_bounds__(1024) void prefsuf_fused(
    const float* __restrict__ hidden,
    float* __restrict__ pref,
    float* __restrict__ suff)
{
    __shared__ float4 pm[NCHUNK][32];   // 16 KB: becomes inclusive prefix
    __shared__ float4 sm[NCHUNK][32];   // 16 KB: becomes inclusive suffix

    const int b     = blockIdx.x;
    const int slice = blockIdx.y;
    const int t     = threadIdx.x;
    const int c     = t >> 5;           // chunk 0..31
    const int j     = t & 31;           // float4-col 0..31
    const int col   = slice * SLICE + 4 * j;

    // chunk-max: 16 strided loads (independent addresses, fmax-chained)
    const float* base = hidden + ((size_t)b * S_LEN + (size_t)c * CHUNK) * HDIM + col;
    float4 m = make_float4(-FLT_MAX, -FLT_MAX, -FLT_MAX, -FLT_MAX);
    #pragma unroll
    for (int s = 0; s < CHUNK; ++s)
        fmax4(m, *reinterpret_cast<const float4*>(base + (size_t)s * HDIM));

    pm[c][j] = m;
    sm[c][j] = m;
    __syncthreads();

    // Hillis-Steele inclusive max-scan: pm forward, sm backward. 5 rounds.
    #pragma unroll
    for (int d = 1; d < NCHUNK; d <<= 1) {
        float4 a = pm[c][j];
        if (c >= d)          fmax4(a, pm[c - d][j]);
        float4 s = sm[c][j];
        if (c + d < NCHUNK)  fmax4(s, sm[c + d][j]);
        __syncthreads();
        pm[c][j] = a;
        sm[c][j] = s;
        __syncthreads();
    }

    // write out: pref[b][c+1] = incl-prefix(c); pref[b][0] = -inf
    //            suff[b][c]   = incl-suffix(c); suff[b][32] = -inf
    const float4 ninf = make_float4(-FLT_MAX, -FLT_MAX, -FLT_MAX, -FLT_MAX);
    float* pb = pref + ((size_t)b * PSDIM) * HDIM + col;
    float* sb = suff + ((size_t)b * PSDIM) * HDIM + col;

    *reinterpret_cast<float4*>(pb + (size_t)(c + 1) * HDIM) = pm[c][j];
    *reinterpret_cast<float4*>(sb + (size_t)c * HDIM)       = sm[c][j];
    if (c == 0)
        *reinterpret_cast<float4*>(pb) = ninf;
    if (c == NCHUNK - 1)
        *reinterpret_cast<float4*>(sb + (size_t)NCHUNK * HDIM) = ninf;
}

// ---- K2: pool (pref/suff + single cut-chunk, 4 row-teams) + GEMM (16 waves).
__global__ __launch_bounds__(1024) void pool_gemm3(
    const float* __restrict__ hidden,
    const float* __restrict__ pref,
    const float* __restrict__ suff,
    const float* __restrict__ W,
    const float* __restrict__ bias,
    const int*   __restrict__ cand_batch,
    const int*   __restrict__ cand_cut,
    float*       __restrict__ out)
{
    __shared__ float partL[4][HDIM];     // 16 KB
    __shared__ float partR[4][HDIM];     // 16 KB
    __shared__ float pooled[2 * HDIM];   // 8 KB
    __shared__ float gpart[16][NLAB];    // 2.2 KB

    const int n   = blockIdx.x;
    const int t   = threadIdx.x;         // 0..1023
    const int g   = t >> 8;              // row-team 0..3
    const int tt  = t & 255;             // -> cols 4tt..4tt+3
    const int col = 4 * tt;
    const int b   = cand_batch[n];
    const int cut = cand_cut[n];                 // block-uniform
    const int fcL = cut >> 4;                    // chunks [0,fcL) fully left
    const int rem = cut & 15;
    const int fcR = fcL + (rem ? 1 : 0);         // chunks [fcR,32) fully right

    float4 mL = make_float4(-FLT_MAX, -FLT_MAX, -FLT_MAX, -FLT_MAX);
    float4 mR = mL;

    // precomputed prefix/suffix rows (teams 0 and 1 only)
    if (g == 0)
        mL = *reinterpret_cast<const float4*>(
            pref + ((size_t)b * PSDIM + fcL) * HDIM + col);
    else if (g == 1)
        mR = *reinterpret_cast<const float4*>(
            suff + ((size_t)b * PSDIM + fcR) * HDIM + col);

    // rows of the single chunk containing the cut, team-strided
    if (rem) {
        const int base16 = fcL * CHUNK;
        const float* hbase = hidden + (size_t)b * S_LEN * HDIM + col;
        #pragma unroll
        for (int i = 0; i < 4; ++i) {
            const int s = base16 + g + 4 * i;
            const float4 v = *reinterpret_cast<const float4*>(hbase + (size_t)s * HDIM);
            if (s < cut) fmax4(mL, v); else fmax4(mR, v);
        }
    }

    *reinterpret_cast<float4*>(&partL[g][col]) = mL;
    *reinterpret_cast<float4*>(&partR[g][col]) = mR;
    __syncthreads();

    // 4-way combine: thread t handles pooled cols {t, t+1024}
    pooled[t] = fmaxf(fmaxf(partL[0][t], partL[1][t]),
                      fmaxf(partL[2][t], partL[3][t]));
    pooled[HDIM + t] = fmaxf(fmaxf(partR[0][t], partR[1][t]),
                             fmaxf(partR[2][t], partR[3][t]));
    __syncthreads();

    // GEMM: wave w owns k in [128w, 128w+128); lanes 0..33 own a label.
    const int w    = t >> 6;                     // 0..15
    const int lane = t & 63;
    if (lane < NLAB) {
        const float* p  = pooled + 128 * w;
        const float* Wp = W + (size_t)(128 * w) * NLAB + lane;
        float acc = 0.0f;
        #pragma unroll 8
        for (int k = 0; k < 128; ++k)
            acc = fmaf(p[k], Wp[(size_t)k * NLAB], acc);
        gpart[w][lane] = acc;
    }
    __syncthreads();

    if (t < NLAB) {
        float s = bias[t];
        #pragma unroll
        for (int w2 = 0; w2 < 16; ++w2) s += gpart[w2][t];
        out[(size_t)n * NLAB + t] = s;
    }
}

// ---- Fallback: proven single-kernel path (only if ws too small).
__global__ __launch_bounds__(256) void dmbert_pool_gemm(
    const float* __restrict__ hidden,
    const float* __restrict__ W,
    const float* __restrict__ bias,
    const int*   __restrict__ cand_batch,
    const int*   __restrict__ cand_cut,
    float*       __restrict__ out)
{
    __shared__ float pooled[2 * HDIM];
    __shared__ float partial[4][NLAB];

    const int n   = blockIdx.x;
    const int t   = threadIdx.x;
    const int bi  = cand_batch[n];
    const int cut = cand_cut[n];

    const float* base = hidden + (size_t)bi * S_LEN * HDIM + 4 * t;
    float4 mL = make_float4(-FLT_MAX, -FLT_MAX, -FLT_MAX, -FLT_MAX);
    float4 mR = mL;

    #pragma unroll 4
    for (int s = 0; s < cut; ++s)
        fmax4(mL, *reinterpret_cast<const float4*>(base + (size_t)s * HDIM));
    #pragma unroll 4
    for (int s = cut; s < S_LEN; ++s)
        fmax4(mR, *reinterpret_cast<const float4*>(base + (size_t)s * HDIM));

    *reinterpret_cast<float4*>(&pooled[4 * t])        = mL;
    *reinterpret_cast<float4*>(&pooled[HDIM + 4 * t]) = mR;
    __syncthreads();

    const int w    = t >> 6;
    const int lane = t & 63;
    if (lane < NLAB) {
        const int k0 = w * (2 * HDIM / 4);
        float acc = 0.0f;
        #pragma unroll 8
        for (int k = k0; k < k0 + (2 * HDIM / 4); ++k)
            acc = fmaf(pooled[k], W[(size_t)k * NLAB + lane], acc);
        partial[w][lane] = acc;
    }
    __syncthreads();

    if (t < NLAB) {
        out[(size_t)n * NLAB + t] =
            partial[0][t] + partial[1][t] + partial[2][t] + partial[3][t] + bias[t];
    }
}

extern "C" void kernel_launch(void* const* d_in, const int* in_sizes, int n_in,
                              void* d_out, int out_size, void* d_ws, size_t ws_size,
                              hipStream_t stream) {
    const float* hidden = (const float*)d_in[0];
    const float* W      = (const float*)d_in[1];
    const float* bias   = (const float*)d_in[2];
    const int*   cb     = (const int*)d_in[3];
    const int*   cc     = (const int*)d_in[4];
    float*       outp   = (float*)d_out;

    const int ncand = in_sizes[3];                       // 256
    const int B     = in_sizes[0] / (S_LEN * HDIM);      // 32
    const size_t ps_elems  = (size_t)B * PSDIM * HDIM;   // 1.056M floats each
    const size_t ws_needed = 2 * ps_elems * sizeof(float);  // ~8.65 MB

    if (ws_size >= ws_needed) {
        float* pref = (float*)d_ws;
        float* suff = pref + ps_elems;
        prefsuf_fused<<<dim3(B, HDIM / SLICE), 1024, 0, stream>>>(hidden, pref, suff);
        pool_gemm3<<<ncand, 1024, 0, stream>>>(hidden, pref, suff, W, bias, cb, cc, outp);
    } else {
        dmbert_pool_gemm<<<ncand, 256, 0, stream>>>(hidden, W, bias, cb, cc, outp);
    }
}